// Round 9
// baseline (244.212 us; speedup 1.0000x reference)
//
#include <hip/hip_runtime.h>
#include <hip/hip_bf16.h>

typedef __bf16 bf16x8 __attribute__((ext_vector_type(8)));
typedef __bf16 bf16x4 __attribute__((ext_vector_type(4)));
typedef float f32x4 __attribute__((ext_vector_type(4)));
typedef float f32x8 __attribute__((ext_vector_type(8)));

#define B_ 8
#define L_ 1024
#define D_ 1024
#define H_ 16
#define DPH_ 64
#define MAXREL_ 32
#define NREL_ 65

__device__ __forceinline__ f32x4 mfma16x16x32(bf16x8 a, bf16x8 b, f32x4 c) {
    return __builtin_amdgcn_mfma_f32_16x16x32_bf16(a, b, c, 0, 0, 0);
}

__device__ __forceinline__ bf16x8 ld_any(const float* p) {
    f32x8 v = *(const f32x8*)p;
    bf16x8 r;
    #pragma unroll
    for (int i = 0; i < 8; ++i) r[i] = (__bf16)v[i];
    return r;
}
__device__ __forceinline__ bf16x8 ld_any(const __bf16* p) { return *(const bf16x8*)p; }

// ---------------------------------------------------------------------------
// 128x128-tile GEMM (R5-proven). LDS XOR-swizzled staging + reg prefetch.
// MODE 0: bf16 out[m*N+n]; MODE 1: bf16 Vt[(m>>10)<<20 | n*1024 | m&1023];
// MODE 2: f32 out[m*N+n].
// ---------------------------------------------------------------------------
template <int MODE, typename TA>
__global__ __launch_bounds__(256) void gemm128(
    const TA* __restrict__ X, const float* __restrict__ Wt,
    const float* __restrict__ bias, void* __restrict__ outp,
    int M, int N, int K, float scale)
{
    __shared__ __bf16 sA[128 * 64];
    __shared__ __bf16 sB[128 * 64];

    const int tid = threadIdx.x;
    const int nbn = N >> 7;
    const int nwg = (M >> 7) * nbn;
    const int wg  = ((int)blockIdx.x & 7) * (nwg >> 3) + ((int)blockIdx.x >> 3);
    const int row0 = (wg / nbn) * 128, col0 = (wg % nbn) * 128;
    const int lane = tid & 63, w = tid >> 6, lr = lane & 15, lk = lane >> 4;
    const int wm = w >> 1, wn = w & 1;
    const int srow = tid >> 3;
    const int schk = tid & 7;

    bf16x8 ra[4], rb[4];
    f32x4 acc[4][4];
    #pragma unroll
    for (int a = 0; a < 4; ++a)
        #pragma unroll
        for (int b = 0; b < 4; ++b) acc[a][b] = (f32x4){0.f, 0.f, 0.f, 0.f};

    const int nkt = K >> 6;
    {
        const int kc = schk * 8;
        #pragma unroll
        for (int u = 0; u < 4; ++u) {
            const int r = u * 32 + srow;
            ra[u] = ld_any(X  + (size_t)(row0 + r) * K + kc);
            rb[u] = ld_any(Wt + (size_t)(col0 + r) * K + kc);
        }
    }
    for (int kt = 0; kt < nkt; ++kt) {
        __syncthreads();
        #pragma unroll
        for (int u = 0; u < 4; ++u) {
            const int r = u * 32 + srow;
            *(bf16x8*)&sA[r * 64 + ((schk ^ (r & 7)) * 8)] = ra[u];
            *(bf16x8*)&sB[r * 64 + ((schk ^ (r & 7)) * 8)] = rb[u];
        }
        __syncthreads();
        if (kt + 1 < nkt) {
            const int kc = (kt + 1) * 64 + schk * 8;
            #pragma unroll
            for (int u = 0; u < 4; ++u) {
                const int r = u * 32 + srow;
                ra[u] = ld_any(X  + (size_t)(row0 + r) * K + kc);
                rb[u] = ld_any(Wt + (size_t)(col0 + r) * K + kc);
            }
        }
        #pragma unroll
        for (int kk = 0; kk < 2; ++kk) {
            bf16x8 af[4], bf[4];
            #pragma unroll
            for (int mi = 0; mi < 4; ++mi) {
                const int r = wm * 64 + mi * 16 + lr;
                af[mi] = *(const bf16x8*)&sA[r * 64 + (((kk * 4 + lk) ^ (r & 7)) * 8)];
            }
            #pragma unroll
            for (int ni = 0; ni < 4; ++ni) {
                const int r = wn * 64 + ni * 16 + lr;
                bf[ni] = *(const bf16x8*)&sB[r * 64 + (((kk * 4 + lk) ^ (r & 7)) * 8)];
            }
            #pragma unroll
            for (int mi = 0; mi < 4; ++mi)
                #pragma unroll
                for (int ni = 0; ni < 4; ++ni)
                    acc[mi][ni] = mfma16x16x32(af[mi], bf[ni], acc[mi][ni]);
        }
    }

    #pragma unroll
    for (int ni = 0; ni < 4; ++ni) {
        const int n = col0 + wn * 64 + ni * 16 + lr;
        const float bv = bias[n];
        #pragma unroll
        for (int mi = 0; mi < 4; ++mi) {
            const int m0 = row0 + wm * 64 + mi * 16 + lk * 4;
            if (MODE == 0) {
                #pragma unroll
                for (int i = 0; i < 4; ++i)
                    ((__bf16*)outp)[(size_t)(m0 + i) * N + n] =
                        (__bf16)((acc[mi][ni][i] + bv) * scale);
            } else if (MODE == 1) {
                bf16x4 v4;
                #pragma unroll
                for (int i = 0; i < 4; ++i) v4[i] = (__bf16)(acc[mi][ni][i] + bv);
                *(bf16x4*)((__bf16*)outp + ((size_t)(m0 >> 10) << 20)
                           + (size_t)n * L_ + (m0 & 1023)) = v4;
            } else {
                #pragma unroll
                for (int i = 0; i < 4; ++i)
                    ((float*)outp)[(size_t)(m0 + i) * N + n] = acc[mi][ni][i] + bv;
            }
        }
    }
}

// ---------------------------------------------------------------------------
// Attention v6: block = (b, h, 128 q-rows), 8 waves (512 thr); wave w owns
// q-rows [w*16, w*16+16) across ALL 1024 keys (v5's verified wave-local path).
// K/V staged once per block (shared by 8 waves): half the global traffic and
// half the staging/barrier cost per q-row vs v5. LDS ~69KB -> 2 blocks/CU
// (16 waves/CU). setprio(1) around MFMA clusters.
// ---------------------------------------------------------------------------
__global__ __launch_bounds__(512, 4) void attn_v6(
    const __bf16* __restrict__ Q, const __bf16* __restrict__ K,
    const __bf16* __restrict__ Vt, const int* __restrict__ mask,
    const float* __restrict__ relg, __bf16* __restrict__ ctx,
    float* __restrict__ attn0)
{
    __shared__ __bf16 sK[2][64 * 64];     // [key][d], chunk-swizzled
    __shared__ __bf16 sV[2][64 * 64];     // [d][key], chunk-swizzled
    __shared__ __bf16 s_rq[128 * 72];     // rq[qlocal][j], bf16
    __shared__ __bf16 s_arel[128 * 72];   // arel[qlocal][bucket], bf16
    __shared__ float s_sums[128];
    __shared__ unsigned s_mbits[32];

    const int tid = threadIdx.x;
    const int wg = ((int)blockIdx.x & 7) * 128 + ((int)blockIdx.x >> 3);
    const int qt = wg & 7, h = (wg >> 3) & 15, b = wg >> 7;
    const int q0 = qt * 128;
    const int lane = tid & 63, w = tid >> 6, lr = lane & 15, lk = lane >> 4;
    const size_t bh = (size_t)b * (L_ * D_) + (size_t)h * DPH_;
    const int ql = w * 16;                // wave's q base (block-local)
    const int qw = q0 + ql;               // wave's q base (global)

    // staging geometry: thread t -> row tid>>3 (0..63), swizzled chunk
    const int strow = tid >> 3;
    const int scg   = (tid & 7) ^ (strow & 7);   // pre-swizzled global chunk
    const __bf16* Kgp = K + bh + (size_t)strow * D_ + scg * 8;
    const __bf16* Vgp = Vt + ((size_t)b << 20)
                      + (size_t)(h * DPH_ + strow) * L_ + scg * 8;

    // Q fragments: lane lr -> q-row qw+lr
    const __bf16* qp = Q + bh + (size_t)(qw + lr) * D_ + 8 * lk;
    const bf16x8 qf0 = *(const bf16x8*)qp;
    const bf16x8 qf1 = *(const bf16x8*)(qp + 32);

    // ---- setup: mask bitset, zero arel, rq via MFMA, preload tile 0 ----
    #pragma unroll
    for (int rr = 0; rr < 2; ++rr) {
        const int k = rr * 512 + w * 64 + lane;
        const unsigned long long bal = __ballot(mask[b * L_ + k] != 0);
        if (lane == 0) {
            s_mbits[rr * 16 + w * 2]     = (unsigned)bal;
            s_mbits[rr * 16 + w * 2 + 1] = (unsigned)(bal >> 32);
        }
    }
    for (int i = tid; i < 128 * 72; i += 512) s_arel[i] = (__bf16)0.f;

    #pragma unroll
    for (int jt = 0; jt < 5; ++jt) {             // each wave: all j for its rows
        const int jr = jt * 16 + lr;
        const int jc = jr > 64 ? 64 : jr;
        const float* rp = relg + jc * 64 + 8 * lk;
        f32x4 rq = {0.f, 0.f, 0.f, 0.f};
        rq = mfma16x16x32(ld_any(rp), qf0, rq);
        rq = mfma16x16x32(ld_any(rp + 32), qf1, rq);
        #pragma unroll
        for (int i = 0; i < 4; ++i) {
            const int jj = jt * 16 + lk * 4 + i;
            if (jj <= 64) s_rq[(ql + lr) * 72 + jj] = (__bf16)rq[i];
        }
    }

    bf16x8 rk0 = *(const bf16x8*)(Kgp);
    bf16x8 rv0 = *(const bf16x8*)(Vgp);
    __syncthreads();   // barrier A

    const float rq0  = (float)s_rq[(ql + lr) * 72 + 0];
    const float rq64 = (float)s_rq[(ql + lr) * 72 + 64];

    float sum = 0.f, c0 = 0.f, c64 = 0.f;
    f32x4 pvacc[4];
    #pragma unroll
    for (int dt = 0; dt < 4; ++dt) pvacc[dt] = (f32x4){0.f, 0.f, 0.f, 0.f};
    float* a0p = attn0 + ((size_t)b * L_ + qw + lr) * L_;
    const int sw = lr & 7;
    const int s0l = lr + 32 * (lk & 1);
    const int s1l = s0l + 16;
    const bool hisel = (lk >> 1) != 0;

    for (int it = 0; it < 16; ++it) {
        const int cur = it & 1;
        const int k0 = it * 64;
        // write prefetched regs -> LDS (linear dest; source pre-swizzled)
        {
            __bf16* kd = &sK[cur][tid * 8];
            __bf16* vd = &sV[cur][tid * 8];
            *(bf16x8*)kd = rk0;
            *(bf16x8*)vd = rv0;
        }
        __syncthreads();   // single barrier per tile (dbuf)
        if (it < 15) {
            rk0 = *(const bf16x8*)(Kgp + (size_t)(k0 + 64) * D_);
            rv0 = *(const bf16x8*)(Vgp + k0 + 64);
        }

        const __bf16* kb = sK[cur];
        const __bf16* vb = sV[cur];

        // ---- QK^T: p[kt][i] = S(q=qw+lr, key=k0+kt*16+lk*4+i) ----
        float p[4][4];
        __builtin_amdgcn_s_setprio(1);
        #pragma unroll
        for (int kt = 0; kt < 4; ++kt) {
            const int rb = (kt * 16 + lr) * 64;
            const bf16x8 a0 = *(const bf16x8*)&kb[rb + ((lk ^ sw) * 8)];
            const bf16x8 a1 = *(const bf16x8*)&kb[rb + (((lk + 4) ^ sw) * 8)];
            f32x4 acc = {0.f, 0.f, 0.f, 0.f};
            acc = mfma16x16x32(a0, qf0, acc);
            acc = mfma16x16x32(a1, qf1, acc);
            #pragma unroll
            for (int i = 0; i < 4; ++i) p[kt][i] = acc[i];
        }
        __builtin_amdgcn_s_setprio(0);

        // ---- bias + mask + exp + sums + arel ----
        const unsigned mw0 = s_mbits[it * 2];
        const unsigned mw1 = s_mbits[it * 2 + 1];
        const int side = (k0 <= qw - 95) ? -1 : ((k0 >= qw + 47) ? 1 : 0);
        if (side == 0) {
            #pragma unroll
            for (int kt = 0; kt < 4; ++kt) {
                const unsigned mword = kt < 2 ? mw0 : mw1;
                #pragma unroll
                for (int i = 0; i < 4; ++i) {
                    const int k = k0 + kt * 16 + lk * 4 + i;
                    const int dd = k - (qw + lr);
                    int j = dd + MAXREL_;
                    j = j < 0 ? 0 : (j > 64 ? 64 : j);
                    const float bias = (float)s_rq[(ql + lr) * 72 + j];
                    const float e = ((mword >> (k & 31)) & 1u)
                                  ? 0.f : __expf(p[kt][i] + bias);
                    p[kt][i] = e;
                    sum += e;
                    if (dd <= -MAXREL_)      c0  += e;
                    else if (dd >= MAXREL_)  c64 += e;
                    else s_arel[(ql + lr) * 72 + dd + MAXREL_] = (__bf16)e;
                }
            }
        } else {
            const float bias = side < 0 ? rq0 : rq64;
            float cacc = 0.f;
            #pragma unroll
            for (int kt = 0; kt < 4; ++kt) {
                const unsigned mword = kt < 2 ? mw0 : mw1;
                #pragma unroll
                for (int i = 0; i < 4; ++i) {
                    const int k = k0 + kt * 16 + lk * 4 + i;
                    const float e = ((mword >> (k & 31)) & 1u)
                                  ? 0.f : __expf(p[kt][i] + bias);
                    p[kt][i] = e;
                    cacc += e;
                }
            }
            sum += cacc;
            if (side < 0) c0 += cacc; else c64 += cacc;
        }

        // ---- attn0 (h==0): unnormalized now, rescaled at end ----
        if (h == 0) {
            #pragma unroll
            for (int kt = 0; kt < 4; ++kt) {
                f32x4 st;
                #pragma unroll
                for (int i = 0; i < 4; ++i) st[i] = p[kt][i];
                *(f32x4*)&a0p[k0 + kt * 16 + lk * 4] = st;
            }
        }

        // ---- pack p -> bf16 pairs ----
        unsigned pk[4][2];
        #pragma unroll
        for (int kt = 0; kt < 4; ++kt)
            #pragma unroll
            for (int hf = 0; hf < 2; ++hf) {
                union { unsigned u; __bf16 x[2]; } t;
                t.x[0] = (__bf16)p[kt][2 * hf];
                t.x[1] = (__bf16)p[kt][2 * hf + 1];
                pk[kt][hf] = t.u;
            }

        // ---- PV: 2 x 32-key steps; A-frag via shuffles (v4 recipe) ----
        #pragma unroll
        for (int s = 0; s < 2; ++s) {
            union { unsigned u[4]; bf16x8 v; } ua;
            {
                const unsigned aE0 = __shfl((int)pk[2 * s][0],     s0l, 64);
                const unsigned aO0 = __shfl((int)pk[2 * s + 1][0], s0l, 64);
                const unsigned aE1 = __shfl((int)pk[2 * s][1],     s0l, 64);
                const unsigned aO1 = __shfl((int)pk[2 * s + 1][1], s0l, 64);
                const unsigned bE0 = __shfl((int)pk[2 * s][0],     s1l, 64);
                const unsigned bO0 = __shfl((int)pk[2 * s + 1][0], s1l, 64);
                const unsigned bE1 = __shfl((int)pk[2 * s][1],     s1l, 64);
                const unsigned bO1 = __shfl((int)pk[2 * s + 1][1], s1l, 64);
                ua.u[0] = hisel ? aO0 : aE0;
                ua.u[1] = hisel ? aO1 : aE1;
                ua.u[2] = hisel ? bO0 : bE0;
                ua.u[3] = hisel ? bO1 : bE1;
            }
            __builtin_amdgcn_s_setprio(1);
            #pragma unroll
            for (int dt = 0; dt < 4; ++dt) {
                const bf16x8 bfv = *(const bf16x8*)
                    &vb[(dt * 16 + lr) * 64 + (((4 * s + lk) ^ sw) * 8)];
                pvacc[dt] = mfma16x16x32(ua.v, bfv, pvacc[dt]);
            }
            __builtin_amdgcn_s_setprio(0);
        }
    }

    // ---- wave-local sums + edge buckets ----
    sum += __shfl_xor(sum, 16, 64); sum += __shfl_xor(sum, 32, 64);
    c0  += __shfl_xor(c0, 16, 64);  c0  += __shfl_xor(c0, 32, 64);
    c64 += __shfl_xor(c64, 16, 64); c64 += __shfl_xor(c64, 32, 64);
    if (lane < 16) {
        s_sums[ql + lr] = sum;
        s_arel[(ql + lr) * 72 + 0]  = (__bf16)c0;
        s_arel[(ql + lr) * 72 + 64] = (__bf16)c64;
    }
    __syncthreads();

    // ---- stage relT[d][j] over sK arena ----
    __bf16* rT = (__bf16*)sK;      // [64][72]
    for (int i = tid; i < NREL_ * DPH_; i += 512)
        rT[(i & 63) * 72 + (i >> 6)] = (__bf16)relg[i];
    __syncthreads();

    // ---- rel-term MFMAs + j=64 rank-1 + normalize + store ctx ----
    const bf16x8 af1 = *(const bf16x8*)&s_arel[(ql + lr) * 72 + 8 * lk];
    const bf16x8 af2 = *(const bf16x8*)&s_arel[(ql + lr) * 72 + 32 + 8 * lk];
    float a64[4], inv[4];
    #pragma unroll
    for (int i = 0; i < 4; ++i) {
        a64[i] = (float)s_arel[(ql + lk * 4 + i) * 72 + 64];
        inv[i] = 1.f / s_sums[ql + lk * 4 + i];
    }
    #pragma unroll
    for (int dt = 0; dt < 4; ++dt) {
        const bf16x8 b1 = *(const bf16x8*)&rT[(dt * 16 + lr) * 72 + 8 * lk];
        const bf16x8 b2 = *(const bf16x8*)&rT[(dt * 16 + lr) * 72 + 32 + 8 * lk];
        pvacc[dt] = mfma16x16x32(af1, b1, pvacc[dt]);
        pvacc[dt] = mfma16x16x32(af2, b2, pvacc[dt]);
        const float r64 = (float)rT[(dt * 16 + lr) * 72 + 64];
        #pragma unroll
        for (int i = 0; i < 4; ++i) {
            const float outv = (pvacc[dt][i] + a64[i] * r64) * inv[i];
            ctx[((size_t)b * L_ + q0 + ql + lk * 4 + i) * D_
                + h * DPH_ + dt * 16 + lr] = (__bf16)outv;
        }
    }

    // ---- attn0 rescale (h==0 blocks only) ----
    if (h == 0) {
        #pragma unroll 4
        for (int n = 0; n < 16; ++n) {
            const float invr = 1.f / s_sums[ql + n];
            float* ap = attn0 + ((size_t)b * L_ + q0 + ql + n) * L_ + lane * 16;
            #pragma unroll
            for (int c = 0; c < 4; ++c) {
                f32x4 v = *(f32x4*)&ap[c * 4];
                #pragma unroll
                for (int i = 0; i < 4; ++i) v[i] *= invr;
                *(f32x4*)&ap[c * 4] = v;
            }
        }
    }
}

extern "C" void kernel_launch(void* const* d_in, const int* in_sizes, int n_in,
                              void* d_out, int out_size, void* d_ws, size_t ws_size,
                              hipStream_t stream) {
    const float* key   = (const float*)d_in[0];
    const float* value = (const float*)d_in[1];
    const float* query = (const float*)d_in[2];
    const int*   mask  = (const int*)d_in[3];
    const float* Wq = (const float*)d_in[4];
    const float* bq = (const float*)d_in[5];
    const float* Wk = (const float*)d_in[6];
    const float* bk = (const float*)d_in[7];
    const float* Wv = (const float*)d_in[8];
    const float* bv = (const float*)d_in[9];
    const float* Wo = (const float*)d_in[10];
    const float* bo = (const float*)d_in[11];
    const float* relg = (const float*)d_in[12];

    float* out   = (float*)d_out;
    float* attn0 = out + (size_t)B_ * L_ * D_;

    char* ws = (char*)d_ws;
    __bf16* Qw   = (__bf16*)(ws);
    __bf16* Kw   = (__bf16*)(ws + ((size_t)16 << 20));
    __bf16* Vtw  = (__bf16*)(ws + ((size_t)32 << 20));
    __bf16* Ctxw = (__bf16*)(ws + ((size_t)48 << 20));

    const dim3 blk(256);
    const int M = B_ * L_;
    const int ngemm = (M / 128) * (D_ / 128);   // 512

    gemm128<0, float><<<ngemm, blk, 0, stream>>>(query, Wq, bq, Qw, M, D_, D_, 0.125f);
    gemm128<0, float><<<ngemm, blk, 0, stream>>>(key,   Wk, bk, Kw, M, D_, D_, 1.0f);
    gemm128<1, float><<<ngemm, blk, 0, stream>>>(value, Wv, bv, Vtw, M, D_, D_, 1.0f);

    attn_v6<<<B_ * H_ * (L_ / 128), dim3(512), 0, stream>>>(
        Qw, Kw, Vtw, mask, relg, Ctxw, attn0);

    gemm128<2, __bf16><<<ngemm, blk, 0, stream>>>(Ctxw, Wo, bo, out, M, D_, D_, 1.0f);
}

// Round 10
// 240.507 us; speedup vs baseline: 1.0154x; 1.0154x over previous
//
#include <hip/hip_runtime.h>
#include <hip/hip_bf16.h>

typedef __bf16 bf16x8 __attribute__((ext_vector_type(8)));
typedef __bf16 bf16x4 __attribute__((ext_vector_type(4)));
typedef float f32x4 __attribute__((ext_vector_type(4)));
typedef float f32x8 __attribute__((ext_vector_type(8)));

#define B_ 8
#define L_ 1024
#define D_ 1024
#define H_ 16
#define DPH_ 64
#define MAXREL_ 32
#define NREL_ 65

__device__ __forceinline__ f32x4 mfma16x16x32(bf16x8 a, bf16x8 b, f32x4 c) {
    return __builtin_amdgcn_mfma_f32_16x16x32_bf16(a, b, c, 0, 0, 0);
}

__device__ __forceinline__ bf16x8 ld_any(const float* p) {
    f32x8 v = *(const f32x8*)p;
    bf16x8 r;
    #pragma unroll
    for (int i = 0; i < 8; ++i) r[i] = (__bf16)v[i];
    return r;
}
__device__ __forceinline__ bf16x8 ld_any(const __bf16* p) { return *(const bf16x8*)p; }

// ---------------------------------------------------------------------------
// gemm_v2: 128x256 tile, BK=32, 512 threads / 8 waves (2M x 4N wave grid,
// per-wave 64x64 = 4x4 frags). Double-buffered LDS [rows][40] (16B-aligned
// rows, <=2-way bank aliasing = free). Pipeline per K-tile: compute(buf cur)
// -> cvt+ds_write tile t+1 (loaded last iter) -> issue loads tile t+2 ->
// barrier. Grid = (M/128)*(N/256) = 256 blocks = 1/CU exactly.
// MODE 0: bf16 out[m*N+n]; MODE 1: bf16 Vt[(m>>10)<<20 | n*1024 | m&1023];
// MODE 2: f32 out[m*N+n].
// ---------------------------------------------------------------------------
template <int MODE, typename TA>
__global__ __launch_bounds__(512, 2) void gemm_v2(
    const TA* __restrict__ X, const float* __restrict__ Wt,
    const float* __restrict__ bias, void* __restrict__ outp,
    int M, int N, int K, float scale)
{
    __shared__ __bf16 sA[2][128 * 40];
    __shared__ __bf16 sB[2][256 * 40];

    const int tid = threadIdx.x;
    const int nbn = N >> 8;
    const int wg = (int)blockIdx.x;
    const int row0 = (wg / nbn) * 128, col0 = (wg % nbn) * 256;
    const int lane = tid & 63, w = tid >> 6, lr = lane & 15, lk = lane >> 4;
    const int wm = w >> 2, wn = w & 3;

    // staging map: A: thread -> (row tid>>2, 8 k-elems); B: (row tid>>1, 16 k)
    const int arow = tid >> 2, ak = (tid & 3) * 8;
    const int brow = tid >> 1, bk = (tid & 1) * 16;
    const TA*    agp = X  + (size_t)(row0 + arow) * K + ak;
    const float* bgp = Wt + (size_t)(col0 + brow) * K + bk;

    f32x4 acc[4][4];
    #pragma unroll
    for (int a = 0; a < 4; ++a)
        #pragma unroll
        for (int b = 0; b < 4; ++b) acc[a][b] = (f32x4){0.f, 0.f, 0.f, 0.f};

    // staging registers (raw loads; convert only at write time)
    f32x4 ra0, ra1;          // A (float path)
    bf16x8 rab;              // A (bf16 path)
    f32x4 rb0, rb1, rb2, rb3;

    #define LOADG(t) do {                                                    \
        const int _k0 = (t) * 32;                                            \
        if (sizeof(TA) == 4) {                                               \
            ra0 = *(const f32x4*)((const float*)agp + _k0);                  \
            ra1 = *(const f32x4*)((const float*)agp + _k0 + 4);              \
        } else {                                                             \
            rab = *(const bf16x8*)((const __bf16*)agp + _k0);                \
        }                                                                    \
        rb0 = *(const f32x4*)(bgp + _k0);                                    \
        rb1 = *(const f32x4*)(bgp + _k0 + 4);                                \
        rb2 = *(const f32x4*)(bgp + _k0 + 8);                                \
        rb3 = *(const f32x4*)(bgp + _k0 + 12);                               \
    } while (0)

    #define WRITEL(buf) do {                                                 \
        bf16x8 _av;                                                          \
        if (sizeof(TA) == 4) {                                               \
            _Pragma("unroll")                                                \
            for (int i = 0; i < 4; ++i) {                                    \
                _av[i] = (__bf16)ra0[i]; _av[4 + i] = (__bf16)ra1[i];        \
            }                                                                \
        } else { _av = rab; }                                                \
        *(bf16x8*)&sA[buf][arow * 40 + ak] = _av;                            \
        bf16x8 _bv0, _bv1;                                                   \
        _Pragma("unroll")                                                    \
        for (int i = 0; i < 4; ++i) {                                        \
            _bv0[i] = (__bf16)rb0[i]; _bv0[4 + i] = (__bf16)rb1[i];          \
            _bv1[i] = (__bf16)rb2[i]; _bv1[4 + i] = (__bf16)rb3[i];          \
        }                                                                    \
        *(bf16x8*)&sB[buf][brow * 40 + bk]     = _bv0;                       \
        *(bf16x8*)&sB[buf][brow * 40 + bk + 8] = _bv1;                       \
    } while (0)

    LOADG(0);
    WRITEL(0);
    LOADG(1);
    __syncthreads();

    const int nkt = K >> 5;   // 32
    for (int t = 0; t < nkt; ++t) {
        const int cur = t & 1;
        bf16x8 af[4], bfr[4];
        #pragma unroll
        for (int m = 0; m < 4; ++m)
            af[m] = *(const bf16x8*)&sA[cur][(wm * 64 + m * 16 + lr) * 40 + 8 * lk];
        #pragma unroll
        for (int n = 0; n < 4; ++n)
            bfr[n] = *(const bf16x8*)&sB[cur][(wn * 64 + n * 16 + lr) * 40 + 8 * lk];
        __builtin_amdgcn_s_setprio(1);
        #pragma unroll
        for (int m = 0; m < 4; ++m)
            #pragma unroll
            for (int n = 0; n < 4; ++n)
                acc[m][n] = mfma16x16x32(af[m], bfr[n], acc[m][n]);
        __builtin_amdgcn_s_setprio(0);
        if (t < nkt - 1) {
            WRITEL(cur ^ 1);              // tile t+1 (regs loaded last iter)
            if (t < nkt - 2) LOADG(t + 2);
            __syncthreads();
        }
    }
    #undef LOADG
    #undef WRITEL

    #pragma unroll
    for (int ni = 0; ni < 4; ++ni) {
        const int n = col0 + wn * 64 + ni * 16 + lr;
        const float bv = bias[n];
        #pragma unroll
        for (int mi = 0; mi < 4; ++mi) {
            const int m0 = row0 + wm * 64 + mi * 16 + lk * 4;
            if (MODE == 0) {
                #pragma unroll
                for (int i = 0; i < 4; ++i)
                    ((__bf16*)outp)[(size_t)(m0 + i) * N + n] =
                        (__bf16)((acc[mi][ni][i] + bv) * scale);
            } else if (MODE == 1) {
                bf16x4 v4;
                #pragma unroll
                for (int i = 0; i < 4; ++i) v4[i] = (__bf16)(acc[mi][ni][i] + bv);
                *(bf16x4*)((__bf16*)outp + ((size_t)(m0 >> 10) << 20)
                           + (size_t)n * L_ + (m0 & 1023)) = v4;
            } else {
                #pragma unroll
                for (int i = 0; i < 4; ++i)
                    ((float*)outp)[(size_t)(m0 + i) * N + n] = acc[mi][ni][i] + bv;
            }
        }
    }
}

// ---------------------------------------------------------------------------
// Attention v5 (R8-measured best, verbatim): block = (b, h, 64 q-rows),
// 4 waves; wave w owns q-rows [w*16, w*16+16) across ALL 1024 keys.
// ---------------------------------------------------------------------------
__global__ __launch_bounds__(256, 3) void attn_v5(
    const __bf16* __restrict__ Q, const __bf16* __restrict__ K,
    const __bf16* __restrict__ Vt, const int* __restrict__ mask,
    const float* __restrict__ relg, __bf16* __restrict__ ctx,
    float* __restrict__ attn0)
{
    __shared__ __bf16 sK[2][64 * 64];     // [key][d], chunk-swizzled
    __shared__ __bf16 sV[2][64 * 64];     // [d][key], chunk-swizzled
    __shared__ __bf16 s_rq[64 * 72];      // rq[qlocal][j], bf16
    __shared__ __bf16 s_arel[64 * 72];    // arel[qlocal][bucket], bf16
    __shared__ float s_sums[64];
    __shared__ unsigned s_mbits[32];

    const int tid = threadIdx.x;
    const int wg = ((int)blockIdx.x & 7) * 256 + ((int)blockIdx.x >> 3);
    const int qt = wg & 15, h = (wg >> 4) & 15, b = wg >> 8;
    const int q0 = qt * 64;
    const int lane = tid & 63, w = tid >> 6, lr = lane & 15, lk = lane >> 4;
    const size_t bh = (size_t)b * (L_ * D_) + (size_t)h * DPH_;
    const int qw = q0 + w * 16;           // wave's q base (global)
    const int ql = w * 16;                // wave's q base (block-local)

    const int strow = tid >> 3;                  // 0..31
    const int scg   = (tid & 7) ^ (strow & 7);   // pre-swizzled global chunk
    const __bf16* Kgp = K + bh + (size_t)strow * D_ + scg * 8;
    const __bf16* Vgp = Vt + ((size_t)b << 20)
                      + (size_t)(h * DPH_ + strow) * L_ + scg * 8;

    const __bf16* qp = Q + bh + (size_t)(qw + lr) * D_ + 8 * lk;
    const bf16x8 qf0 = *(const bf16x8*)qp;
    const bf16x8 qf1 = *(const bf16x8*)(qp + 32);

    #pragma unroll
    for (int rr = 0; rr < 4; ++rr) {
        const int k = rr * 256 + w * 64 + lane;
        const unsigned long long bal = __ballot(mask[b * L_ + k] != 0);
        if (lane == 0) {
            s_mbits[rr * 8 + w * 2]     = (unsigned)bal;
            s_mbits[rr * 8 + w * 2 + 1] = (unsigned)(bal >> 32);
        }
    }
    for (int i = tid; i < 64 * 72; i += 256) s_arel[i] = (__bf16)0.f;

    #pragma unroll
    for (int jt = 0; jt < 5; ++jt) {
        const int jr = jt * 16 + lr;
        const int jc = jr > 64 ? 64 : jr;
        const float* rp = relg + jc * 64 + 8 * lk;
        f32x4 rq = {0.f, 0.f, 0.f, 0.f};
        rq = mfma16x16x32(ld_any(rp), qf0, rq);
        rq = mfma16x16x32(ld_any(rp + 32), qf1, rq);
        #pragma unroll
        for (int i = 0; i < 4; ++i) {
            const int jj = jt * 16 + lk * 4 + i;
            if (jj <= 64) s_rq[(ql + lr) * 72 + jj] = (__bf16)rq[i];
        }
    }

    bf16x8 rk0 = *(const bf16x8*)(Kgp);
    bf16x8 rk1 = *(const bf16x8*)(Kgp + 32 * (size_t)D_);
    bf16x8 rv0 = *(const bf16x8*)(Vgp);
    bf16x8 rv1 = *(const bf16x8*)(Vgp + 32 * (size_t)L_);
    __syncthreads();

    const float rq0  = (float)s_rq[(ql + lr) * 72 + 0];
    const float rq64 = (float)s_rq[(ql + lr) * 72 + 64];

    float sum = 0.f, c0 = 0.f, c64 = 0.f;
    f32x4 pvacc[4];
    #pragma unroll
    for (int dt = 0; dt < 4; ++dt) pvacc[dt] = (f32x4){0.f, 0.f, 0.f, 0.f};
    float* a0p = attn0 + ((size_t)b * L_ + qw + lr) * L_;
    const int sw = lr & 7;
    const int s0l = lr + 32 * (lk & 1);
    const int s1l = s0l + 16;
    const bool hisel = (lk >> 1) != 0;

    for (int it = 0; it < 16; ++it) {
        const int cur = it & 1;
        const int k0 = it * 64;
        {
            __bf16* kd = &sK[cur][tid * 8];
            __bf16* vd = &sV[cur][tid * 8];
            *(bf16x8*)kd = rk0;  *(bf16x8*)(kd + 2048) = rk1;
            *(bf16x8*)vd = rv0;  *(bf16x8*)(vd + 2048) = rv1;
        }
        __syncthreads();
        if (it < 15) {
            const size_t ko = (size_t)(k0 + 64) * D_;
            rk0 = *(const bf16x8*)(Kgp + ko);
            rk1 = *(const bf16x8*)(Kgp + ko + 32 * (size_t)D_);
            rv0 = *(const bf16x8*)(Vgp + k0 + 64);
            rv1 = *(const bf16x8*)(Vgp + k0 + 64 + 32 * (size_t)L_);
        }

        const __bf16* kb = sK[cur];
        const __bf16* vb = sV[cur];

        float p[4][4];
        #pragma unroll
        for (int kt = 0; kt < 4; ++kt) {
            const int rb = (kt * 16 + lr) * 64;
            const bf16x8 a0 = *(const bf16x8*)&kb[rb + ((lk ^ sw) * 8)];
            const bf16x8 a1 = *(const bf16x8*)&kb[rb + (((lk + 4) ^ sw) * 8)];
            f32x4 acc = {0.f, 0.f, 0.f, 0.f};
            acc = mfma16x16x32(a0, qf0, acc);
            acc = mfma16x16x32(a1, qf1, acc);
            #pragma unroll
            for (int i = 0; i < 4; ++i) p[kt][i] = acc[i];
        }

        const unsigned mw0 = s_mbits[(k0 >> 5)];
        const unsigned mw1 = s_mbits[(k0 >> 5) + 1];
        const int side = (k0 <= qw - 95) ? -1 : ((k0 >= qw + 47) ? 1 : 0);
        if (side == 0) {
            #pragma unroll
            for (int kt = 0; kt < 4; ++kt) {
                const unsigned mword = kt < 2 ? mw0 : mw1;
                #pragma unroll
                for (int i = 0; i < 4; ++i) {
                    const int k = k0 + kt * 16 + lk * 4 + i;
                    const int dd = k - (qw + lr);
                    int j = dd + MAXREL_;
                    j = j < 0 ? 0 : (j > 64 ? 64 : j);
                    const float bias = (float)s_rq[(ql + lr) * 72 + j];
                    const float e = ((mword >> (k & 31)) & 1u)
                                  ? 0.f : __expf(p[kt][i] + bias);
                    p[kt][i] = e;
                    sum += e;
                    if (dd <= -MAXREL_)      c0  += e;
                    else if (dd >= MAXREL_)  c64 += e;
                    else s_arel[(ql + lr) * 72 + dd + MAXREL_] = (__bf16)e;
                }
            }
        } else {
            const float bias = side < 0 ? rq0 : rq64;
            float cacc = 0.f;
            #pragma unroll
            for (int kt = 0; kt < 4; ++kt) {
                const unsigned mword = kt < 2 ? mw0 : mw1;
                #pragma unroll
                for (int i = 0; i < 4; ++i) {
                    const int k = k0 + kt * 16 + lk * 4 + i;
                    const float e = ((mword >> (k & 31)) & 1u)
                                  ? 0.f : __expf(p[kt][i] + bias);
                    p[kt][i] = e;
                    cacc += e;
                }
            }
            sum += cacc;
            if (side < 0) c0 += cacc; else c64 += cacc;
        }

        if (h == 0) {
            #pragma unroll
            for (int kt = 0; kt < 4; ++kt) {
                f32x4 st;
                #pragma unroll
                for (int i = 0; i < 4; ++i) st[i] = p[kt][i];
                *(f32x4*)&a0p[k0 + kt * 16 + lk * 4] = st;
            }
        }

        unsigned pk[4][2];
        #pragma unroll
        for (int kt = 0; kt < 4; ++kt)
            #pragma unroll
            for (int hf = 0; hf < 2; ++hf) {
                union { unsigned u; __bf16 x[2]; } t;
                t.x[0] = (__bf16)p[kt][2 * hf];
                t.x[1] = (__bf16)p[kt][2 * hf + 1];
                pk[kt][hf] = t.u;
            }

        #pragma unroll
        for (int s = 0; s < 2; ++s) {
            union { unsigned u[4]; bf16x8 v; } ua;
            {
                const unsigned aE0 = __shfl((int)pk[2 * s][0],     s0l, 64);
                const unsigned aO0 = __shfl((int)pk[2 * s + 1][0], s0l, 64);
                const unsigned aE1 = __shfl((int)pk[2 * s][1],     s0l, 64);
                const unsigned aO1 = __shfl((int)pk[2 * s + 1][1], s0l, 64);
                const unsigned bE0 = __shfl((int)pk[2 * s][0],     s1l, 64);
                const unsigned bO0 = __shfl((int)pk[2 * s + 1][0], s1l, 64);
                const unsigned bE1 = __shfl((int)pk[2 * s][1],     s1l, 64);
                const unsigned bO1 = __shfl((int)pk[2 * s + 1][1], s1l, 64);
                ua.u[0] = hisel ? aO0 : aE0;
                ua.u[1] = hisel ? aO1 : aE1;
                ua.u[2] = hisel ? bO0 : bE0;
                ua.u[3] = hisel ? bO1 : bE1;
            }
            #pragma unroll
            for (int dt = 0; dt < 4; ++dt) {
                const bf16x8 bfv = *(const bf16x8*)
                    &vb[(dt * 16 + lr) * 64 + (((4 * s + lk) ^ sw) * 8)];
                pvacc[dt] = mfma16x16x32(ua.v, bfv, pvacc[dt]);
            }
        }
    }

    sum += __shfl_xor(sum, 16, 64); sum += __shfl_xor(sum, 32, 64);
    c0  += __shfl_xor(c0, 16, 64);  c0  += __shfl_xor(c0, 32, 64);
    c64 += __shfl_xor(c64, 16, 64); c64 += __shfl_xor(c64, 32, 64);
    if (lane < 16) {
        s_sums[ql + lr] = sum;
        s_arel[(ql + lr) * 72 + 0]  = (__bf16)c0;
        s_arel[(ql + lr) * 72 + 64] = (__bf16)c64;
    }
    __syncthreads();

    __bf16* rT = (__bf16*)sK;      // [64][72]
    for (int i = tid; i < NREL_ * DPH_; i += 256)
        rT[(i & 63) * 72 + (i >> 6)] = (__bf16)relg[i];
    __syncthreads();

    const bf16x8 af1 = *(const bf16x8*)&s_arel[(ql + lr) * 72 + 8 * lk];
    const bf16x8 af2 = *(const bf16x8*)&s_arel[(ql + lr) * 72 + 32 + 8 * lk];
    float a64[4], inv[4];
    #pragma unroll
    for (int i = 0; i < 4; ++i) {
        a64[i] = (float)s_arel[(ql + lk * 4 + i) * 72 + 64];
        inv[i] = 1.f / s_sums[ql + lk * 4 + i];
    }
    #pragma unroll
    for (int dt = 0; dt < 4; ++dt) {
        const bf16x8 b1 = *(const bf16x8*)&rT[(dt * 16 + lr) * 72 + 8 * lk];
        const bf16x8 b2 = *(const bf16x8*)&rT[(dt * 16 + lr) * 72 + 32 + 8 * lk];
        pvacc[dt] = mfma16x16x32(af1, b1, pvacc[dt]);
        pvacc[dt] = mfma16x16x32(af2, b2, pvacc[dt]);
        const float r64 = (float)rT[(dt * 16 + lr) * 72 + 64];
        #pragma unroll
        for (int i = 0; i < 4; ++i) {
            const float outv = (pvacc[dt][i] + a64[i] * r64) * inv[i];
            ctx[((size_t)b * L_ + q0 + ql + lk * 4 + i) * D_
                + h * DPH_ + dt * 16 + lr] = (__bf16)outv;
        }
    }

    if (h == 0) {
        #pragma unroll 4
        for (int n = 0; n < 16; ++n) {
            const float invr = 1.f / s_sums[ql + n];
            float* ap = attn0 + ((size_t)b * L_ + q0 + ql + n) * L_ + lane * 16;
            #pragma unroll
            for (int c = 0; c < 4; ++c) {
                f32x4 v = *(f32x4*)&ap[c * 4];
                #pragma unroll
                for (int i = 0; i < 4; ++i) v[i] *= invr;
                *(f32x4*)&ap[c * 4] = v;
            }
        }
    }
}

extern "C" void kernel_launch(void* const* d_in, const int* in_sizes, int n_in,
                              void* d_out, int out_size, void* d_ws, size_t ws_size,
                              hipStream_t stream) {
    const float* key   = (const float*)d_in[0];
    const float* value = (const float*)d_in[1];
    const float* query = (const float*)d_in[2];
    const int*   mask  = (const int*)d_in[3];
    const float* Wq = (const float*)d_in[4];
    const float* bq = (const float*)d_in[5];
    const float* Wk = (const float*)d_in[6];
    const float* bk = (const float*)d_in[7];
    const float* Wv = (const float*)d_in[8];
    const float* bv = (const float*)d_in[9];
    const float* Wo = (const float*)d_in[10];
    const float* bo = (const float*)d_in[11];
    const float* relg = (const float*)d_in[12];

    float* out   = (float*)d_out;
    float* attn0 = out + (size_t)B_ * L_ * D_;

    char* ws = (char*)d_ws;
    __bf16* Qw   = (__bf16*)(ws);
    __bf16* Kw   = (__bf16*)(ws + ((size_t)16 << 20));
    __bf16* Vtw  = (__bf16*)(ws + ((size_t)32 << 20));
    __bf16* Ctxw = (__bf16*)(ws + ((size_t)48 << 20));

    const int M = B_ * L_;
    const int ngemm = (M / 128) * (D_ / 256);   // 256 blocks = 1/CU

    gemm_v2<0, float><<<ngemm, dim3(512), 0, stream>>>(query, Wq, bq, Qw, M, D_, D_, 0.125f);
    gemm_v2<0, float><<<ngemm, dim3(512), 0, stream>>>(key,   Wk, bk, Kw, M, D_, D_, 1.0f);
    gemm_v2<1, float><<<ngemm, dim3(512), 0, stream>>>(value, Wv, bv, Vtw, M, D_, D_, 1.0f);

    attn_v5<<<B_ * H_ * (L_ / 64), dim3(256), 0, stream>>>(
        Qw, Kw, Vtw, mask, relg, Ctxw, attn0);

    gemm_v2<2, __bf16><<<ngemm, dim3(512), 0, stream>>>(Ctxw, Wo, bo, out, M, D_, D_, 1.0f);
}